// Round 3
// baseline (240.406 us; speedup 1.0000x reference)
//
#include <hip/hip_runtime.h>

// ---------- types ----------
typedef __attribute__((ext_vector_type(8))) __bf16 bf16x8;
typedef __attribute__((ext_vector_type(4))) float  f32x4;

__device__ __forceinline__ unsigned short f2bf(float f) {
    unsigned int u = __builtin_bit_cast(unsigned int, f);
    u += 0x7fffu + ((u >> 16) & 1u);          // RNE
    return (unsigned short)(u >> 16);
}
__device__ __forceinline__ unsigned int pack2(float a, float b) {
    return (unsigned int)f2bf(a) | ((unsigned int)f2bf(b) << 16);
}

// swizzled element offset for a [row][64 bf16] LDS tile (128B rows).
// 16B chunks XOR-permuted by row&7 -> conflict-free column fragment reads (G4/T2).
__device__ __forceinline__ int swz8(int row, int chunk) {
    return row * 64 + ((chunk ^ (row & 7)) << 3);
}

// async 16B/lane global->LDS (linear dest = wave-uniform base + lane*16B)
__device__ __forceinline__ void gload16(const unsigned short* g, unsigned short* l) {
    __builtin_amdgcn_global_load_lds((const __attribute__((address_space(1))) void*)g,
                                     (__attribute__((address_space(3))) void*)l, 16, 0, 0);
}
// stage 32 rows x 64 cols bf16 (rows [wv*32, wv*32+32)) from row-major g (+kt pre-applied)
__device__ __forceinline__ void stage_async(const unsigned short* g, int ldg,
                                            unsigned short* ldsbase, int lane, int wv) {
    const unsigned short* gp = g + (size_t)(wv * 32 + (lane >> 3)) * ldg + (lane & 7) * 8;
#pragma unroll
    for (int i = 0; i < 4; ++i)
        gload16(gp + (size_t)(i * 8) * ldg, ldsbase + (wv * 32 + i * 8) * 64);
}

// ---------- reg staging (f32 sources), 128 rows x 64 k ----------
struct RegTileF32 { float4 r[4][2]; };
__device__ __forceinline__ void load_direct_f32(RegTileF32& rt, const float* base, int kt, int tid) {
#pragma unroll
    for (int s = 0; s < 4; ++s) {
        int idx = tid + s * 256, row = idx >> 3, ch = idx & 7;
        const float* gp = base + (size_t)row * 512 + kt + ch * 8;
        rt.r[s][0] = *(const float4*)gp;
        rt.r[s][1] = *(const float4*)(gp + 4);
    }
}
__device__ __forceinline__ void write_direct(const RegTileF32& rt, unsigned short* lds, int tid) {
#pragma unroll
    for (int s = 0; s < 4; ++s) {
        int idx = tid + s * 256, row = idx >> 3, ch = idx & 7;
        uint4 w;
        w.x = pack2(rt.r[s][0].x, rt.r[s][0].y); w.y = pack2(rt.r[s][0].z, rt.r[s][0].w);
        w.z = pack2(rt.r[s][1].x, rt.r[s][1].y); w.w = pack2(rt.r[s][1].z, rt.r[s][1].w);
        *(uint4*)(&lds[swz8(row, ch)]) = w;
    }
}
// q transpose staging: q[b] is [512 c][1024 p]; tile = [128 p][64 c]
struct RegTileQ { float r[2][4][4]; };  // [s][i=c][j=p]
__device__ __forceinline__ void load_trans_q(RegTileQ& rt, const float* qb, int m0, int kt, int tid) {
#pragma unroll
    for (int s = 0; s < 2; ++s) {
        int qi = tid + s * 256, pq = qi & 31, cq = qi >> 5;
        const float* gp = qb + (size_t)(kt + cq * 4) * 1024 + m0 + pq * 4;
#pragma unroll
        for (int i = 0; i < 4; ++i) {
            float4 vv = *(const float4*)(gp + (size_t)i * 1024);
            rt.r[s][i][0] = vv.x; rt.r[s][i][1] = vv.y; rt.r[s][i][2] = vv.z; rt.r[s][i][3] = vv.w;
        }
    }
}
__device__ __forceinline__ void write_trans_q(const RegTileQ& rt, unsigned short* lds, int tid) {
#pragma unroll
    for (int s = 0; s < 2; ++s) {
        int qi = tid + s * 256, pq = qi & 31, cq = qi >> 5;
#pragma unroll
        for (int j = 0; j < 4; ++j) {
            int row = pq * 4 + j;
            uint2 w2;
            w2.x = pack2(rt.r[s][0][j], rt.r[s][1][j]);
            w2.y = pack2(rt.r[s][2][j], rt.r[s][3][j]);
            *(uint2*)(&lds[row * 64 + (((cq >> 1) ^ (row & 7)) << 3) + (cq & 1) * 4]) = w2;
        }
    }
}

#define GEMM_COMPUTE(AsB, BsB)                                                       \
    _Pragma("unroll")                                                                \
    for (int kk = 0; kk < 2; ++kk) {                                                 \
        bf16x8 af[4], bfr[4];                                                        \
        _Pragma("unroll")                                                            \
        for (int i = 0; i < 4; ++i) {                                                \
            int rr_ = r0 + i * 16 + (lane & 15);                                     \
            af[i] = *(const bf16x8*)(&(AsB)[swz8(rr_, kk * 4 + (lane >> 4))]);       \
        }                                                                            \
        _Pragma("unroll")                                                            \
        for (int j = 0; j < 4; ++j) {                                                \
            int rr_ = c0 + j * 16 + (lane & 15);                                     \
            bfr[j] = *(const bf16x8*)(&(BsB)[swz8(rr_, kk * 4 + (lane >> 4))]);      \
        }                                                                            \
        _Pragma("unroll")                                                            \
        for (int i = 0; i < 4; ++i)                                                  \
            _Pragma("unroll")                                                        \
            for (int j = 0; j < 4; ++j)                                              \
                acc[i][j] = __builtin_amdgcn_mfma_f32_16x16x32_bf16(af[i], bfr[j],   \
                                                                   acc[i][j], 0, 0, 0); \
    }

// ---------- weight pre-convert: f32 -> bf16, PRE-SWIZZLED per 64-k window ----------
__global__ __launch_bounds__(256) void ck_w(const float* __restrict__ Wv, const float* __restrict__ Wk,
                                            const float* __restrict__ Wq, const float* __restrict__ Wm,
                                            unsigned short* __restrict__ W4) {
    int gi = blockIdx.x * 256 + threadIdx.x;     // 131072 chunks of 8
    int w = gi >> 15, idx = gi & 32767;
    const float* src = (w == 0) ? Wv : (w == 1) ? Wk : (w == 2) ? Wq : Wm;
    int row = idx >> 6, ch = idx & 63;
    int chs = (ch & ~7) | ((ch ^ row) & 7);
    const float* gp = src + (size_t)row * 512 + ch * 8;
    float4 v0 = *(const float4*)gp, v1 = *(const float4*)(gp + 4);
    uint4 o;
    o.x = pack2(v0.x, v0.y); o.y = pack2(v0.z, v0.w);
    o.z = pack2(v1.x, v1.y); o.w = pack2(v1.z, v1.w);
    *(uint4*)(W4 + ((size_t)w << 18) + (size_t)row * 512 + chs * 8) = o;
}

// ---------- K/V projection: C[bl,o] = X[bl,:]·W[o,:] + b -> bf16 [b][n][l][64] ----------
template<bool BW4>
__global__ __launch_bounds__(256) void g_proj_kv(const float* __restrict__ X,
                                                 const float* __restrict__ Wf,
                                                 const unsigned short* __restrict__ Wh,
                                                 const float* __restrict__ bias,
                                                 unsigned short* __restrict__ out) {
    __shared__ alignas(16) unsigned short As[2][128 * 64];
    __shared__ alignas(16) unsigned short Bs[2][128 * 64];
    int tid = threadIdx.x, lane = tid & 63, wv = tid >> 6;
    int m0 = blockIdx.x * 128, n0 = blockIdx.y * 128;
    int r0 = (wv >> 1) * 64, c0 = (wv & 1) * 64;
    f32x4 acc[4][4] = {};
    const float* Ab = X + (size_t)m0 * 512;

    RegTileF32 ra, rb;
    load_direct_f32(ra, Ab, 0, tid);
    if (!BW4) load_direct_f32(rb, Wf + (size_t)n0 * 512, 0, tid);
    write_direct(ra, As[0], tid);
    if (!BW4) write_direct(rb, Bs[0], tid);
    else stage_async(Wh + (size_t)n0 * 512, 512, Bs[0], lane, wv);
    __syncthreads();
#pragma unroll
    for (int t = 0; t < 8; ++t) {
        int cur = t & 1, nxt = cur ^ 1;
        if (t < 7) {
            load_direct_f32(ra, Ab, (t + 1) * 64, tid);
            if (!BW4) load_direct_f32(rb, Wf + (size_t)n0 * 512, (t + 1) * 64, tid);
            else stage_async(Wh + (size_t)n0 * 512 + (t + 1) * 64, 512, Bs[nxt], lane, wv);
        }
        GEMM_COMPUTE(As[cur], Bs[cur]);
        if (t < 7) {
            write_direct(ra, As[nxt], tid);
            if (!BW4) write_direct(rb, Bs[nxt], tid);
            __syncthreads();
        }
    }
#pragma unroll
    for (int j = 0; j < 4; ++j) {
        int o = n0 + c0 + j * 16 + (lane & 15);
        float bb = bias[o];
        int n = o >> 6, d = o & 63;
#pragma unroll
        for (int i = 0; i < 4; ++i) {
#pragma unroll
            for (int reg = 0; reg < 4; ++reg) {
                int r = m0 + r0 + i * 16 + ((lane >> 4) << 2) + reg;
                out[(((size_t)((r >> 10) * 8 + n)) * 1024 + (r & 1023)) * 64 + d] =
                    f2bf(acc[i][j][reg] + bb);
            }
        }
    }
}

// ---------- Q projection (transposed A): C[p,o] = sum_c q[b,c,p]·Wq[o,c], x1/8 ----------
template<bool BW4>
__global__ __launch_bounds__(256) void g_proj_q(const float* __restrict__ Q,
                                                const float* __restrict__ Wf,
                                                const unsigned short* __restrict__ Wh,
                                                const float* __restrict__ bq,
                                                unsigned short* __restrict__ qh) {
    __shared__ alignas(16) unsigned short As[2][128 * 64];
    __shared__ alignas(16) unsigned short Bs[2][128 * 64];
    int tid = threadIdx.x, lane = tid & 63, wv = tid >> 6;
    int b = blockIdx.z;
    int m0 = blockIdx.x * 128, n0 = blockIdx.y * 128;
    int r0 = (wv >> 1) * 64, c0 = (wv & 1) * 64;
    f32x4 acc[4][4] = {};
    const float* Qb = Q + (size_t)b * 512 * 1024;

    RegTileQ ra;
    RegTileF32 rb;
    load_trans_q(ra, Qb, m0, 0, tid);
    if (!BW4) load_direct_f32(rb, Wf + (size_t)n0 * 512, 0, tid);
    write_trans_q(ra, As[0], tid);
    if (!BW4) write_direct(rb, Bs[0], tid);
    else stage_async(Wh + (size_t)n0 * 512, 512, Bs[0], lane, wv);
    __syncthreads();
#pragma unroll
    for (int t = 0; t < 8; ++t) {
        int cur = t & 1, nxt = cur ^ 1;
        if (t < 7) {
            load_trans_q(ra, Qb, m0, (t + 1) * 64, tid);
            if (!BW4) load_direct_f32(rb, Wf + (size_t)n0 * 512, (t + 1) * 64, tid);
            else stage_async(Wh + (size_t)n0 * 512 + (t + 1) * 64, 512, Bs[nxt], lane, wv);
        }
        GEMM_COMPUTE(As[cur], Bs[cur]);
        if (t < 7) {
            write_trans_q(ra, As[nxt], tid);
            if (!BW4) write_direct(rb, Bs[nxt], tid);
            __syncthreads();
        }
    }
#pragma unroll
    for (int j = 0; j < 4; ++j) {
        int o = n0 + c0 + j * 16 + (lane & 15);
        float bb = bq[o];
        int n = o >> 6, d = o & 63;
#pragma unroll
        for (int i = 0; i < 4; ++i) {
#pragma unroll
            for (int reg = 0; reg < 4; ++reg) {
                int p = m0 + r0 + i * 16 + ((lane >> 4) << 2) + reg;
                qh[(((size_t)(b * 8 + n)) * 1024 + p) * 64 + d] =
                    f2bf((acc[i][j][reg] + bb) * 0.125f);  // fold 1/sqrt(64)
            }
        }
    }
}

// ---------- staging helpers for attn (64 rows x 64, 256 threads) ----------
__device__ __forceinline__ void stage_direct_bf16(unsigned short* lds, const unsigned short* g,
                                                  int ldg, int tid) {
#pragma unroll
    for (int s = 0; s < 2; ++s) {
        int idx = tid + s * 256;
        int row = idx >> 3, c = idx & 7;
        uint4 v = *(const uint4*)(g + (size_t)row * ldg + c * 8);
        *(uint4*)(lds + swz8(row, c)) = v;
    }
}
__device__ __forceinline__ void stage_trans_bf16(unsigned short* lds, const unsigned short* g,
                                                 int ldg, int tid) {
    int tk = (tid >> 4) * 4;
    int tn = (tid & 15) * 4;
    unsigned short rr[4][4];
#pragma unroll
    for (int i = 0; i < 4; ++i) {
        ushort4 v = *(const ushort4*)(g + (size_t)(tk + i) * ldg + tn);
        rr[i][0] = v.x; rr[i][1] = v.y; rr[i][2] = v.z; rr[i][3] = v.w;
    }
#pragma unroll
    for (int j = 0; j < 4; ++j) {
        int row = tn + j;
        ushort4 w4;
        w4.x = rr[0][j]; w4.y = rr[1][j]; w4.z = rr[2][j]; w4.w = rr[3][j];
        int off = row * 64 + (((tk >> 3) ^ (row & 7)) << 3) + (tk & 7);
        *(ushort4*)(lds + off) = w4;
    }
}
__device__ __forceinline__ bf16x8 fragld(const unsigned short* lds, int row, int kk, int lane) {
    return *(const bf16x8*)(lds + swz8(row, kk * 4 + (lane >> 4)));
}

// ---------- flash attention (unchanged core; epilogue -> attnT[b][p][c] pre-swizzled) ----------
__global__ __launch_bounds__(256) void k_attn(const unsigned short* __restrict__ qh,
                                              const unsigned short* __restrict__ kh,
                                              const unsigned short* __restrict__ vh,
                                              const int* __restrict__ mask,
                                              unsigned short* __restrict__ attnT) {
    __shared__ alignas(16) unsigned short Qs[64 * 64];
    __shared__ alignas(16) unsigned short Ks[64 * 64];
    __shared__ alignas(16) unsigned short Vs[64 * 64];   // transposed: [d][l]
    __shared__ alignas(16) unsigned short Ps[4][16 * 64];
    int tid = threadIdx.x, lane = tid & 63, wv = tid >> 6;
    int bn = blockIdx.x;
    int b = bn >> 3, n = bn & 7;
    int p0 = blockIdx.y * 64;
    const unsigned short* qbase = qh + (((size_t)bn) * 1024 + p0) * 64;
    const unsigned short* kbase = kh + ((size_t)bn) * 1024 * 64;
    const unsigned short* vbase = vh + ((size_t)bn) * 1024 * 64;
    const int* mbase = mask + (size_t)b * 1024;

    stage_direct_bf16(Qs, qbase, 64, tid);
    __syncthreads();
    bf16x8 aq0 = fragld(Qs, wv * 16 + (lane & 15), 0, lane);
    bf16x8 aq1 = fragld(Qs, wv * 16 + (lane & 15), 1, lane);

    float mrow[4], lrow[4];
    f32x4 o4[4] = {};
#pragma unroll
    for (int r = 0; r < 4; ++r) { mrow[r] = -3e38f; lrow[r] = 0.f; }

    for (int t = 0; t < 16; ++t) {
        int l0 = t * 64;
        __syncthreads();
        stage_direct_bf16(Ks, kbase + (size_t)l0 * 64, 64, tid);
        stage_trans_bf16(Vs, vbase + (size_t)l0 * 64, 64, tid);
        __syncthreads();

        f32x4 s[4] = {};
#pragma unroll
        for (int j = 0; j < 4; ++j) {
            bf16x8 bk0 = fragld(Ks, j * 16 + (lane & 15), 0, lane);
            bf16x8 bk1 = fragld(Ks, j * 16 + (lane & 15), 1, lane);
            s[j] = __builtin_amdgcn_mfma_f32_16x16x32_bf16(aq0, bk0, s[j], 0, 0, 0);
            s[j] = __builtin_amdgcn_mfma_f32_16x16x32_bf16(aq1, bk1, s[j], 0, 0, 0);
        }
#pragma unroll
        for (int j = 0; j < 4; ++j) {
            if (mbase[l0 + j * 16 + (lane & 15)] != 0) {
#pragma unroll
                for (int reg = 0; reg < 4; ++reg) s[j][reg] = -1e9f;
            }
        }
        float pv[4][4], corr[4];
#pragma unroll
        for (int reg = 0; reg < 4; ++reg) {
            float mx = fmaxf(fmaxf(s[0][reg], s[1][reg]), fmaxf(s[2][reg], s[3][reg]));
#pragma unroll
            for (int off = 1; off < 16; off <<= 1) mx = fmaxf(mx, __shfl_xor(mx, off, 64));
            float mnew = fmaxf(mrow[reg], mx);
            corr[reg] = __expf(mrow[reg] - mnew);
            mrow[reg] = mnew;
            float sum = 0.f;
#pragma unroll
            for (int j = 0; j < 4; ++j) {
                float p = __expf(s[j][reg] - mnew);
                pv[j][reg] = p;
                sum += p;
            }
#pragma unroll
            for (int off = 1; off < 16; off <<= 1) sum += __shfl_xor(sum, off, 64);
            lrow[reg] = lrow[reg] * corr[reg] + sum;
        }
        unsigned short* Pw = Ps[wv];
#pragma unroll
        for (int j = 0; j < 4; ++j) {
            int c = j * 16 + (lane & 15);
#pragma unroll
            for (int reg = 0; reg < 4; ++reg) {
                int pr = ((lane >> 4) << 2) + reg;
                Pw[pr * 64 + (((c >> 3) ^ (pr & 7)) << 3) + (c & 7)] = f2bf(pv[j][reg]);
            }
        }
#pragma unroll
        for (int jd = 0; jd < 4; ++jd)
#pragma unroll
            for (int reg = 0; reg < 4; ++reg) o4[jd][reg] *= corr[reg];
#pragma unroll
        for (int kk = 0; kk < 2; ++kk) {
            bf16x8 ap = fragld(Pw, (lane & 15), kk, lane);
#pragma unroll
            for (int jd = 0; jd < 4; ++jd) {
                bf16x8 bv = fragld(Vs, jd * 16 + (lane & 15), kk, lane);
                o4[jd] = __builtin_amdgcn_mfma_f32_16x16x32_bf16(ap, bv, o4[jd], 0, 0, 0);
            }
        }
    }
    // epilogue: normalize, per-wave LDS transpose to [p][d] (chunk-swizzled by p&7),
    // then linear readback/store -> attnT[b][p][c] arrives pre-swizzled for g_final's
    // global_load_lds staging (rule 21: linear dest + swizzled source + swizzled read).
    float inv[4];
#pragma unroll
    for (int reg = 0; reg < 4; ++reg) inv[reg] = 1.f / lrow[reg];
    unsigned short* Ow = Ps[wv];  // [16 p][8 chunks of 8]
#pragma unroll
    for (int jd = 0; jd < 4; ++jd) {
        int d = jd * 16 + (lane & 15);
        int ch = d >> 3, doff = d & 7;
#pragma unroll
        for (int reg = 0; reg < 4; ++reg) {
            int pr = ((lane >> 4) << 2) + reg;
            Ow[pr * 64 + ((ch ^ (pr & 7)) << 3) + doff] = f2bf(o4[jd][reg] * inv[reg]);
        }
    }
    int row = lane >> 2, m = lane & 3;
    const unsigned short* rb_ = Ow + row * 64 + m * 16;
    uint4 w0 = *(const uint4*)rb_;
    uint4 w1 = *(const uint4*)(rb_ + 8);
    size_t oaddr = ((size_t)b * 1024 + p0 + wv * 16 + row) * 512 + n * 64 + m * 16;
    *(uint4*)(attnT + oaddr) = w0;
    *(uint4*)(attnT + oaddr + 8) = w1;
}

// ---------- final 1x1 conv: C[o,p] = relu(Wm[o,:]·attnT[p,:]^T + bm[o]) -> f32 [b][o][p] ----------
template<bool BW4>
__global__ __launch_bounds__(256) void g_final(const unsigned short* __restrict__ attnT,
                                               const float* __restrict__ Wf,
                                               const unsigned short* __restrict__ Wh,
                                               const float* __restrict__ bm,
                                               float* __restrict__ out) {
    __shared__ alignas(16) unsigned short As[2][128 * 64];
    __shared__ alignas(16) unsigned short Bs[2][128 * 64];
    int tid = threadIdx.x, lane = tid & 63, wv = tid >> 6;
    int b = blockIdx.z;
    int m0 = blockIdx.x * 128;  // o
    int n0 = blockIdx.y * 128;  // p
    int r0 = (wv >> 1) * 64, c0 = (wv & 1) * 64;
    f32x4 acc[4][4] = {};
    const unsigned short* Bb = attnT + ((size_t)b * 1024 + n0) * 512;

    RegTileF32 ra;
    if (!BW4) {
        load_direct_f32(ra, Wf + (size_t)m0 * 512, 0, tid);
        write_direct(ra, As[0], tid);
    } else {
        stage_async(Wh + (size_t)m0 * 512, 512, As[0], lane, wv);
    }
    stage_async(Bb, 512, Bs[0], lane, wv);
    __syncthreads();
#pragma unroll
    for (int t = 0; t < 8; ++t) {
        int cur = t & 1, nxt = cur ^ 1;
        if (t < 7) {
            if (!BW4) load_direct_f32(ra, Wf + (size_t)m0 * 512, (t + 1) * 64, tid);
            else stage_async(Wh + (size_t)m0 * 512 + (t + 1) * 64, 512, As[nxt], lane, wv);
            stage_async(Bb + (t + 1) * 64, 512, Bs[nxt], lane, wv);
        }
        GEMM_COMPUTE(As[cur], Bs[cur]);
        if (t < 7) {
            if (!BW4) write_direct(ra, As[nxt], tid);
            __syncthreads();
        }
    }
#pragma unroll
    for (int i = 0; i < 4; ++i) {
#pragma unroll
        for (int reg = 0; reg < 4; ++reg) {
            int o = m0 + r0 + i * 16 + ((lane >> 4) << 2) + reg;
            float bb = bm[o];
#pragma unroll
            for (int j = 0; j < 4; ++j) {
                int p = n0 + c0 + j * 16 + (lane & 15);
                out[((size_t)(b * 512 + o)) * 1024 + p] = fmaxf(acc[i][j][reg] + bb, 0.f);
            }
        }
    }
}

extern "C" void kernel_launch(void* const* d_in, const int* in_sizes, int n_in,
                              void* d_out, int out_size, void* d_ws, size_t ws_size,
                              hipStream_t stream) {
    const float* v  = (const float*)d_in[0];
    const float* k  = (const float*)d_in[1];
    const float* q  = (const float*)d_in[2];
    const int*   mask = (const int*)d_in[3];   // JAX bool -> int32
    const float* Wv = (const float*)d_in[4];
    const float* bv = (const float*)d_in[5];
    const float* Wk = (const float*)d_in[6];
    const float* bk = (const float*)d_in[7];
    const float* Wq = (const float*)d_in[8];
    const float* bq = (const float*)d_in[9];
    const float* Wm = (const float*)d_in[10];
    const float* bm = (const float*)d_in[11];
    float* out = (float*)d_out;

    const size_t E = (size_t)8 * 8 * 1024 * 64;  // 4,194,304 elems (8MB) per region
    unsigned short* kh    = (unsigned short*)d_ws;
    unsigned short* vh    = kh + E;
    unsigned short* qh    = vh + E;
    unsigned short* attnT = qh + E;
    unsigned short* W4    = attnT + E;           // 4x 512*512 bf16 = 2MB, pre-swizzled
    const size_t WSZ = (size_t)512 * 512;
    bool useW4 = ws_size >= (4 * E + 4 * WSZ) * sizeof(unsigned short);

    dim3 blk(256);
    if (useW4) {
        ck_w<<<512, blk, 0, stream>>>(Wv, Wk, Wq, Wm, W4);
        g_proj_kv<true><<<dim3(64, 4),   blk, 0, stream>>>(k, Wk, W4 + WSZ,     bk, kh);
        g_proj_kv<true><<<dim3(64, 4),   blk, 0, stream>>>(v, Wv, W4,           bv, vh);
        g_proj_q<true> <<<dim3(8, 4, 8), blk, 0, stream>>>(q, Wq, W4 + 2 * WSZ, bq, qh);
    } else {
        g_proj_kv<false><<<dim3(64, 4),   blk, 0, stream>>>(k, Wk, nullptr, bk, kh);
        g_proj_kv<false><<<dim3(64, 4),   blk, 0, stream>>>(v, Wv, nullptr, bv, vh);
        g_proj_q<false> <<<dim3(8, 4, 8), blk, 0, stream>>>(q, Wq, nullptr, bq, qh);
    }
    k_attn<<<dim3(64, 16), blk, 0, stream>>>(qh, kh, vh, mask, attnT);
    if (useW4) g_final<true> <<<dim3(4, 8, 8), blk, 0, stream>>>(attnT, Wm, W4 + 3 * WSZ, bm, out);
    else       g_final<false><<<dim3(4, 8, 8), blk, 0, stream>>>(attnT, Wm, nullptr, bm, out);
}

// Round 4
// 238.435 us; speedup vs baseline: 1.0083x; 1.0083x over previous
//
#include <hip/hip_runtime.h>

// ---------- types ----------
typedef __attribute__((ext_vector_type(8))) __bf16 bf16x8;
typedef __attribute__((ext_vector_type(4))) float  f32x4;

#define SCALE_Q 0.1803368801111204f   // 0.125 * log2(e): QK^T comes out in log2 units
#define THR_L2  11.541560327111708f   // defer-max threshold: 8 * log2(e)

__device__ __forceinline__ unsigned short f2bf(float f) {
    unsigned int u = __builtin_bit_cast(unsigned int, f);
    u += 0x7fffu + ((u >> 16) & 1u);          // RNE
    return (unsigned short)(u >> 16);
}
__device__ __forceinline__ unsigned int pack2(float a, float b) {
    return (unsigned int)f2bf(a) | ((unsigned int)f2bf(b) << 16);
}

// element offset in a [rows][512 bf16] LDS tile, 8-elem-chunk XOR-swizzled (G4/T2)
__device__ __forceinline__ int idxW(int row, int ch) {
    return row * 512 + (((ch & ~7) | ((ch ^ row) & 7)) << 3);
}
// element offset in a [rows][64 bf16] LDS tile, chunk-swizzled
__device__ __forceinline__ int swz8(int row, int chunk) {
    return row * 64 + ((chunk ^ (row & 7)) << 3);
}
__device__ __forceinline__ bf16x8 fragld(const unsigned short* lds, int row, int kk, int lane) {
    return *(const bf16x8*)(lds + swz8(row, kk * 4 + (lane >> 4)));
}

// ---------- weight pre-pack: f32 -> bf16 fragment-native ----------
// Wp[w][ (nb*16+kb)*64 + lane ][8] = W[nb*16 + (lane&15)][kb*32 + (lane>>4)*8 + jj]
__global__ __launch_bounds__(256) void ck_w(const float* __restrict__ Wv, const float* __restrict__ Wk,
                                            const float* __restrict__ Wq, const float* __restrict__ Wm,
                                            unsigned short* __restrict__ Wp) {
    int tid = threadIdx.x, lane = tid & 63;
    int gw = blockIdx.x * 4 + (tid >> 6);       // 2048 wave-tasks
    int w = gw >> 9, rem = gw & 511;
    int nb = rem >> 4, kb = rem & 15;
    const float* src = (w == 0) ? Wv : (w == 1) ? Wk : (w == 2) ? Wq : Wm;
    const float* gp = src + (size_t)(nb * 16 + (lane & 15)) * 512 + kb * 32 + (lane >> 4) * 8;
    float4 v0 = *(const float4*)gp, v1 = *(const float4*)(gp + 4);
    uint4 o;
    o.x = pack2(v0.x, v0.y); o.y = pack2(v0.z, v0.w);
    o.z = pack2(v1.x, v1.y); o.w = pack2(v1.z, v1.w);
    *(uint4*)(Wp + ((size_t)w << 18) + ((size_t)((nb * 16 + kb) * 64 + lane)) * 8) = o;
}

// ---------- fused projection GEMM: one barrier total, B LDS-free ----------
// pid<128: kh from k; <256: vh from v; else qh (transposed A) from q.
__global__ __launch_bounds__(256, 2) void g_proj(const float* __restrict__ kin,
                                                 const float* __restrict__ vin,
                                                 const float* __restrict__ qin,
                                                 const unsigned short* __restrict__ Wp,
                                                 const float* __restrict__ bk,
                                                 const float* __restrict__ bv,
                                                 const float* __restrict__ bq,
                                                 unsigned short* __restrict__ kh,
                                                 unsigned short* __restrict__ vh,
                                                 unsigned short* __restrict__ qh) {
    __shared__ alignas(16) unsigned short As[64 * 512];   // 64 KB
    int tid = threadIdx.x, lane = tid & 63, wv = tid >> 6;
    int pid = blockIdx.x;
    int srcSel = (pid < 128) ? 0 : (pid < 256) ? 1 : 2;

    if (srcSel < 2) {
        int panel = (srcSel == 0) ? pid : pid - 128;
        const float* src = ((srcSel == 0) ? kin : vin) + (size_t)panel * 64 * 512;
#pragma unroll
        for (int it = 0; it < 16; ++it) {
            int id = it * 256 + tid, row = id >> 6, ch = id & 63;
            const float* gp = src + (size_t)row * 512 + ch * 8;
            float4 a0 = *(const float4*)gp, a1 = *(const float4*)(gp + 4);
            uint4 w;
            w.x = pack2(a0.x, a0.y); w.y = pack2(a0.z, a0.w);
            w.z = pack2(a1.x, a1.y); w.w = pack2(a1.z, a1.w);
            *(uint4*)(&As[idxW(row, ch)]) = w;
        }
    } else {
        int qi = pid - 256, b = qi >> 4, pp = qi & 15;
        const float* src = qin + (size_t)b * 512 * 1024 + pp * 64;
#pragma unroll
        for (int cc = 0; cc < 8; ++cc) {
            int c0 = cc * 64 + (tid >> 4) * 4;
            int pl = (tid & 15) * 4;
            float rr[4][4];
#pragma unroll
            for (int i = 0; i < 4; ++i) {
                float4 t4 = *(const float4*)(src + (size_t)(c0 + i) * 1024 + pl);
                rr[i][0] = t4.x; rr[i][1] = t4.y; rr[i][2] = t4.z; rr[i][3] = t4.w;
            }
#pragma unroll
            for (int j = 0; j < 4; ++j) {
                int row = pl + j, chunk = c0 >> 3, off = c0 & 7;
                uint2 w2;
                w2.x = pack2(rr[0][j], rr[1][j]);
                w2.y = pack2(rr[2][j], rr[3][j]);
                *(uint2*)(&As[row * 512 + (((chunk & ~7) | ((chunk ^ row) & 7)) << 3) + off]) = w2;
            }
        }
    }
    __syncthreads();

    int wsel = (srcSel == 0) ? 1 : (srcSel == 1) ? 0 : 2;   // pack order [Wv,Wk,Wq,Wm]
    const unsigned short* Wb = Wp + ((size_t)wsel << 18);
    f32x4 acc[4][8] = {};
#pragma unroll 2
    for (int kb = 0; kb < 16; ++kb) {
        bf16x8 af[4];
#pragma unroll
        for (int i = 0; i < 4; ++i)
            af[i] = *(const bf16x8*)(&As[idxW(i * 16 + (lane & 15), kb * 4 + (lane >> 4))]);
#pragma unroll
        for (int j = 0; j < 8; ++j) {
            bf16x8 bf8 = *(const bf16x8*)(Wb + ((size_t)(((wv * 8 + j) * 16 + kb) * 64 + lane)) * 8);
#pragma unroll
            for (int i = 0; i < 4; ++i)
                acc[i][j] = __builtin_amdgcn_mfma_f32_16x16x32_bf16(af[i], bf8, acc[i][j], 0, 0, 0);
        }
    }

    if (srcSel < 2) {
        int panel = (srcSel == 0) ? pid : pid - 128;
        unsigned short* dst = (srcSel == 0) ? kh : vh;
        const float* bias = (srcSel == 0) ? bk : bv;
#pragma unroll
        for (int j = 0; j < 8; ++j) {
            int o = wv * 128 + j * 16 + (lane & 15);
            float bb = bias[o];
            int n = o >> 6, d = o & 63;
#pragma unroll
            for (int i = 0; i < 4; ++i)
#pragma unroll
                for (int reg = 0; reg < 4; ++reg) {
                    int r = panel * 64 + i * 16 + ((lane >> 4) << 2) + reg;
                    dst[(((size_t)((r >> 10) * 8 + n)) * 1024 + (r & 1023)) * 64 + d] =
                        f2bf(acc[i][j][reg] + bb);
                }
        }
    } else {
        int qi = pid - 256, b = qi >> 4, pp = qi & 15;
#pragma unroll
        for (int j = 0; j < 8; ++j) {
            int o = wv * 128 + j * 16 + (lane & 15);
            float bb = bq[o];
            int n = o >> 6, d = o & 63;
#pragma unroll
            for (int i = 0; i < 4; ++i)
#pragma unroll
                for (int reg = 0; reg < 4; ++reg) {
                    int p = pp * 64 + i * 16 + ((lane >> 4) << 2) + reg;
                    qh[(((size_t)(b * 8 + n)) * 1024 + p) * 64 + d] =
                        f2bf((acc[i][j][reg] + bb) * SCALE_Q);   // fold 1/8 * log2e
                }
        }
    }
}

// ---------- attn staging helpers (64x64) ----------
__device__ __forceinline__ void stage_direct_bf16(unsigned short* lds, const unsigned short* g,
                                                  int ldg, int tid) {
#pragma unroll
    for (int s = 0; s < 2; ++s) {
        int idx = tid + s * 256;
        int row = idx >> 3, c = idx & 7;
        uint4 v = *(const uint4*)(g + (size_t)row * ldg + c * 8);
        *(uint4*)(lds + swz8(row, c)) = v;
    }
}
__device__ __forceinline__ void stage_trans_bf16(unsigned short* lds, const unsigned short* g,
                                                 int ldg, int tid) {
    int tk = (tid >> 4) * 4;
    int tn = (tid & 15) * 4;
    unsigned short rr[4][4];
#pragma unroll
    for (int i = 0; i < 4; ++i) {
        ushort4 v = *(const ushort4*)(g + (size_t)(tk + i) * ldg + tn);
        rr[i][0] = v.x; rr[i][1] = v.y; rr[i][2] = v.z; rr[i][3] = v.w;
    }
#pragma unroll
    for (int j = 0; j < 4; ++j) {
        int row = tn + j;
        ushort4 w4;
        w4.x = rr[0][j]; w4.y = rr[1][j]; w4.z = rr[2][j]; w4.w = rr[3][j];
        int off = row * 64 + (((tk >> 3) ^ (row & 7)) << 3) + (tk & 7);
        *(ushort4*)(lds + off) = w4;
    }
}

// ---------- flash attention (exp2 domain; defer-max; frag-native output over qh) ----------
__global__ __launch_bounds__(256) void k_attn(unsigned short* qa,   // qh in, attnP out (alias)
                                              const unsigned short* __restrict__ kh,
                                              const unsigned short* __restrict__ vh,
                                              const int* __restrict__ mask) {
    __shared__ alignas(16) unsigned short Qs[64 * 64];
    __shared__ alignas(16) unsigned short Ks[64 * 64];
    __shared__ alignas(16) unsigned short Vs[64 * 64];   // transposed: [d][l]
    __shared__ alignas(16) unsigned short Ps[4][16 * 64];
    int tid = threadIdx.x, lane = tid & 63, wv = tid >> 6;
    int bn = blockIdx.x;
    int b = bn >> 3;
    int p0 = blockIdx.y * 64;
    const unsigned short* kbase = kh + ((size_t)bn) * 1024 * 64;
    const unsigned short* vbase = vh + ((size_t)bn) * 1024 * 64;
    const int* mbase = mask + (size_t)b * 1024;

    stage_direct_bf16(Qs, qa + (((size_t)bn) * 1024 + p0) * 64, 64, tid);
    __syncthreads();
    bf16x8 aq0 = fragld(Qs, wv * 16 + (lane & 15), 0, lane);
    bf16x8 aq1 = fragld(Qs, wv * 16 + (lane & 15), 1, lane);

    float mrow[4], lrow[4];
    f32x4 o4[4] = {};
#pragma unroll
    for (int r = 0; r < 4; ++r) { mrow[r] = -3e38f; lrow[r] = 0.f; }

    for (int t = 0; t < 16; ++t) {
        int l0 = t * 64;
        __syncthreads();
        stage_direct_bf16(Ks, kbase + (size_t)l0 * 64, 64, tid);
        stage_trans_bf16(Vs, vbase + (size_t)l0 * 64, 64, tid);
        __syncthreads();

        f32x4 s[4] = {};
#pragma unroll
        for (int j = 0; j < 4; ++j) {
            bf16x8 bk0 = fragld(Ks, j * 16 + (lane & 15), 0, lane);
            bf16x8 bk1 = fragld(Ks, j * 16 + (lane & 15), 1, lane);
            s[j] = __builtin_amdgcn_mfma_f32_16x16x32_bf16(aq0, bk0, s[j], 0, 0, 0);
            s[j] = __builtin_amdgcn_mfma_f32_16x16x32_bf16(aq1, bk1, s[j], 0, 0, 0);
        }
#pragma unroll
        for (int j = 0; j < 4; ++j) {
            if (mbase[l0 + j * 16 + (lane & 15)] != 0) {
#pragma unroll
                for (int reg = 0; reg < 4; ++reg) s[j][reg] = -1e9f;
            }
        }
        // row max (16-lane groups share a row)
        float mx[4];
        bool ok = true;
#pragma unroll
        for (int reg = 0; reg < 4; ++reg) {
            float m_ = fmaxf(fmaxf(s[0][reg], s[1][reg]), fmaxf(s[2][reg], s[3][reg]));
#pragma unroll
            for (int off = 1; off < 16; off <<= 1) m_ = fmaxf(m_, __shfl_xor(m_, off, 64));
            mx[reg] = m_;
            ok = ok && (m_ <= mrow[reg] + THR_L2);
        }
        float pvv[4][4];
        if (__all(ok)) {           // defer-max fast path: no rescale
#pragma unroll
            for (int reg = 0; reg < 4; ++reg) {
                float sum = 0.f;
#pragma unroll
                for (int j = 0; j < 4; ++j) {
                    float p = exp2f(s[j][reg] - mrow[reg]);
                    pvv[j][reg] = p; sum += p;
                }
#pragma unroll
                for (int off = 1; off < 16; off <<= 1) sum += __shfl_xor(sum, off, 64);
                lrow[reg] += sum;
            }
        } else {
            float corr[4];
#pragma unroll
            for (int reg = 0; reg < 4; ++reg) {
                float mnew = fmaxf(mrow[reg], mx[reg]);
                corr[reg] = exp2f(mrow[reg] - mnew);
                float sum = 0.f;
#pragma unroll
                for (int j = 0; j < 4; ++j) {
                    float p = exp2f(s[j][reg] - mnew);
                    pvv[j][reg] = p; sum += p;
                }
#pragma unroll
                for (int off = 1; off < 16; off <<= 1) sum += __shfl_xor(sum, off, 64);
                lrow[reg] = lrow[reg] * corr[reg] + sum;
                mrow[reg] = mnew;
            }
#pragma unroll
            for (int jd = 0; jd < 4; ++jd)
#pragma unroll
                for (int reg = 0; reg < 4; ++reg) o4[jd][reg] *= corr[reg];
        }
        unsigned short* Pw = Ps[wv];
#pragma unroll
        for (int j = 0; j < 4; ++j) {
            int c = j * 16 + (lane & 15);
#pragma unroll
            for (int reg = 0; reg < 4; ++reg) {
                int pr = ((lane >> 4) << 2) + reg;
                Pw[pr * 64 + (((c >> 3) ^ (pr & 7)) << 3) + (c & 7)] = f2bf(pvv[j][reg]);
            }
        }
#pragma unroll
        for (int kk = 0; kk < 2; ++kk) {
            bf16x8 ap = fragld(Pw, (lane & 15), kk, lane);
#pragma unroll
            for (int jd = 0; jd < 4; ++jd) {
                bf16x8 bvf = fragld(Vs, jd * 16 + (lane & 15), kk, lane);
                o4[jd] = __builtin_amdgcn_mfma_f32_16x16x32_bf16(ap, bvf, o4[jd], 0, 0, 0);
            }
        }
    }
    // epilogue: normalize; per-wave transpose to [p][d]; store frag-native over qh region.
    float inv[4];
#pragma unroll
    for (int reg = 0; reg < 4; ++reg) inv[reg] = 1.f / lrow[reg];
    unsigned short* Ow = Ps[wv];  // [16 p][64 d], chunk-swizzled by p&7
#pragma unroll
    for (int jd = 0; jd < 4; ++jd) {
        int d = jd * 16 + (lane & 15);
        int ch = d >> 3, doff = d & 7;
#pragma unroll
        for (int reg = 0; reg < 4; ++reg) {
            int pr = ((lane >> 4) << 2) + reg;
            Ow[pr * 64 + ((ch ^ (pr & 7)) << 3) + doff] = f2bf(o4[jd][reg] * inv[reg]);
        }
    }
    // frag for (pb = p0/16 + wv, kb = n*2 + h): lane&15 = p, lane>>4 selects d-chunk
    size_t base = ((size_t)bn * 16 + blockIdx.y) * 4096;
#pragma unroll
    for (int h = 0; h < 2; ++h) {
        int p = lane & 15;
        int ch = h * 4 + (lane >> 4);
        uint4 w = *(const uint4*)(&Ow[p * 64 + ((ch ^ (p & 7)) << 3)]);
        *(uint4*)(qa + base + (size_t)(wv * 2 + h) * 512 + (size_t)lane * 8) = w;
    }
}

// ---------- final 1x1 conv: zero-LDS, zero-barrier GEMM + bias + relu ----------
__global__ __launch_bounds__(256, 2) void g_final(const unsigned short* __restrict__ aP,
                                                  const unsigned short* __restrict__ Wm8,
                                                  const float* __restrict__ bm,
                                                  float* __restrict__ out) {
    int tid = threadIdx.x, lane = tid & 63, wv = tid >> 6;
    int wr = wv >> 1, wc = wv & 1;
    int b = blockIdx.z, m0 = blockIdx.x * 128, n0 = blockIdx.y * 128;
    int onb = m0 / 16 + wr * 4;     // A 16-row block base (o)
    int pnb = n0 / 16 + wc * 4;     // B 16-row block base (p)
    f32x4 acc[4][4] = {};
#pragma unroll 2
    for (int kb = 0; kb < 16; ++kb) {
        int nh = kb >> 1, h = kb & 1, bn = b * 8 + nh;
        bf16x8 af[4], bf8[4];
#pragma unroll
        for (int i = 0; i < 4; ++i)
            af[i] = *(const bf16x8*)(Wm8 + ((size_t)(((onb + i) * 16 + kb) * 64 + lane)) * 8);
#pragma unroll
        for (int j = 0; j < 4; ++j) {
            int pb = pnb + j;
            bf8[j] = *(const bf16x8*)(aP + ((size_t)bn * 16 + (pb >> 2)) * 4096 +
                                      (size_t)((pb & 3) * 2 + h) * 512 + (size_t)lane * 8);
        }
#pragma unroll
        for (int i = 0; i < 4; ++i)
#pragma unroll
            for (int j = 0; j < 4; ++j)
                acc[i][j] = __builtin_amdgcn_mfma_f32_16x16x32_bf16(af[i], bf8[j], acc[i][j], 0, 0, 0);
    }
#pragma unroll
    for (int i = 0; i < 4; ++i)
#pragma unroll
        for (int reg = 0; reg < 4; ++reg) {
            int o = m0 + wr * 64 + i * 16 + ((lane >> 4) << 2) + reg;
            float bb = bm[o];
#pragma unroll
            for (int j = 0; j < 4; ++j) {
                int p = n0 + wc * 64 + j * 16 + (lane & 15);
                out[((size_t)(b * 512 + o)) * 1024 + p] = fmaxf(acc[i][j][reg] + bb, 0.f);
            }
        }
}

extern "C" void kernel_launch(void* const* d_in, const int* in_sizes, int n_in,
                              void* d_out, int out_size, void* d_ws, size_t ws_size,
                              hipStream_t stream) {
    const float* v  = (const float*)d_in[0];
    const float* k  = (const float*)d_in[1];
    const float* q  = (const float*)d_in[2];
    const int*   mask = (const int*)d_in[3];   // JAX bool -> int32
    const float* Wv = (const float*)d_in[4];
    const float* bv = (const float*)d_in[5];
    const float* Wk = (const float*)d_in[6];
    const float* bk = (const float*)d_in[7];
    const float* Wq = (const float*)d_in[8];
    const float* bq = (const float*)d_in[9];
    const float* Wm = (const float*)d_in[10];
    const float* bm = (const float*)d_in[11];
    float* out = (float*)d_out;

    const size_t E = (size_t)8 * 8 * 1024 * 64;   // 4,194,304 shorts = 8 MB per region
    unsigned short* kh = (unsigned short*)d_ws;
    unsigned short* vh = kh + E;
    unsigned short* qh = vh + E;                  // attnP aliases qh after k_attn
    unsigned short* Wp = qh + E;                  // 4 x 512KB frag-packed weights
    // total: 26 MB (ws proven >= 32 MB by rounds 2/3)

    dim3 blk(256);
    ck_w  <<<512, blk, 0, stream>>>(Wv, Wk, Wq, Wm, Wp);
    g_proj<<<384, blk, 0, stream>>>(k, v, q, Wp, bk, bv, bq, kh, vh, qh);
    k_attn<<<dim3(64, 16), blk, 0, stream>>>(qh, kh, vh, mask);
    g_final<<<dim3(4, 8, 8), blk, 0, stream>>>(qh, Wp + 3 * 262144, bm, out);
}

// Round 5
// 224.391 us; speedup vs baseline: 1.0714x; 1.0626x over previous
//
#include <hip/hip_runtime.h>

// ---------- types ----------
typedef __attribute__((ext_vector_type(8))) __bf16 bf16x8;
typedef __attribute__((ext_vector_type(4))) float  f32x4;

#define SCALE_Q 0.1803368801111204f   // 0.125 * log2(e): QK^T comes out in log2 units

__device__ __forceinline__ unsigned short f2bf(float f) {
    unsigned int u = __builtin_bit_cast(unsigned int, f);
    u += 0x7fffu + ((u >> 16) & 1u);          // RNE
    return (unsigned short)(u >> 16);
}
__device__ __forceinline__ unsigned int pack2(float a, float b) {
    return (unsigned int)f2bf(a) | ((unsigned int)f2bf(b) << 16);
}

// element offset in a [rows][512 bf16] LDS tile, 8-elem-chunk XOR-swizzled (G4/T2)
__device__ __forceinline__ int idxW(int row, int ch) {
    return row * 512 + (((ch & ~7) | ((ch ^ row) & 7)) << 3);
}
// element offset in a [rows][64 bf16] LDS tile, chunk-swizzled
__device__ __forceinline__ int swz8(int row, int chunk) {
    return row * 64 + ((chunk ^ (row & 7)) << 3);
}
__device__ __forceinline__ bf16x8 fragld(const unsigned short* lds, int row, int kk, int lane) {
    return *(const bf16x8*)(lds + swz8(row, kk * 4 + (lane >> 4)));
}

// ---------- weight pre-pack: f32 -> bf16 fragment-native ----------
__global__ __launch_bounds__(256) void ck_w(const float* __restrict__ Wv, const float* __restrict__ Wk,
                                            const float* __restrict__ Wq, const float* __restrict__ Wm,
                                            unsigned short* __restrict__ Wp) {
    int tid = threadIdx.x, lane = tid & 63;
    int gw = blockIdx.x * 4 + (tid >> 6);       // 2048 wave-tasks
    int w = gw >> 9, rem = gw & 511;
    int nb = rem >> 4, kb = rem & 15;
    const float* src = (w == 0) ? Wv : (w == 1) ? Wk : (w == 2) ? Wq : Wm;
    const float* gp = src + (size_t)(nb * 16 + (lane & 15)) * 512 + kb * 32 + (lane >> 4) * 8;
    float4 v0 = *(const float4*)gp, v1 = *(const float4*)(gp + 4);
    uint4 o;
    o.x = pack2(v0.x, v0.y); o.y = pack2(v0.z, v0.w);
    o.z = pack2(v1.x, v1.y); o.w = pack2(v1.z, v1.w);
    *(uint4*)(Wp + ((size_t)w << 18) + ((size_t)((nb * 16 + kb) * 64 + lane)) * 8) = o;
}

// ---------- fused projection GEMM: one barrier total, B LDS-free ----------
__global__ __launch_bounds__(256, 2) void g_proj(const float* __restrict__ kin,
                                                 const float* __restrict__ vin,
                                                 const float* __restrict__ qin,
                                                 const unsigned short* __restrict__ Wp,
                                                 const float* __restrict__ bk,
                                                 const float* __restrict__ bv,
                                                 const float* __restrict__ bq,
                                                 unsigned short* __restrict__ kh,
                                                 unsigned short* __restrict__ vh,
                                                 unsigned short* __restrict__ qh) {
    __shared__ alignas(16) unsigned short As[64 * 512];   // 64 KB
    int tid = threadIdx.x, lane = tid & 63, wv = tid >> 6;
    int pid = blockIdx.x;
    int srcSel = (pid < 128) ? 0 : (pid < 256) ? 1 : 2;

    if (srcSel < 2) {
        int panel = (srcSel == 0) ? pid : pid - 128;
        const float* src = ((srcSel == 0) ? kin : vin) + (size_t)panel * 64 * 512;
#pragma unroll
        for (int it = 0; it < 16; ++it) {
            int id = it * 256 + tid, row = id >> 6, ch = id & 63;
            const float* gp = src + (size_t)row * 512 + ch * 8;
            float4 a0 = *(const float4*)gp, a1 = *(const float4*)(gp + 4);
            uint4 w;
            w.x = pack2(a0.x, a0.y); w.y = pack2(a0.z, a0.w);
            w.z = pack2(a1.x, a1.y); w.w = pack2(a1.z, a1.w);
            *(uint4*)(&As[idxW(row, ch)]) = w;
        }
    } else {
        int qi = pid - 256, b = qi >> 4, pp = qi & 15;
        const float* src = qin + (size_t)b * 512 * 1024 + pp * 64;
#pragma unroll
        for (int cc = 0; cc < 8; ++cc) {
            int c0 = cc * 64 + (tid >> 4) * 4;
            int pl = (tid & 15) * 4;
            float rr[4][4];
#pragma unroll
            for (int i = 0; i < 4; ++i) {
                float4 t4 = *(const float4*)(src + (size_t)(c0 + i) * 1024 + pl);
                rr[i][0] = t4.x; rr[i][1] = t4.y; rr[i][2] = t4.z; rr[i][3] = t4.w;
            }
#pragma unroll
            for (int j = 0; j < 4; ++j) {
                int row = pl + j, chunk = c0 >> 3, off = c0 & 7;
                uint2 w2;
                w2.x = pack2(rr[0][j], rr[1][j]);
                w2.y = pack2(rr[2][j], rr[3][j]);
                *(uint2*)(&As[row * 512 + (((chunk & ~7) | ((chunk ^ row) & 7)) << 3) + off]) = w2;
            }
        }
    }
    __syncthreads();

    int wsel = (srcSel == 0) ? 1 : (srcSel == 1) ? 0 : 2;   // pack order [Wv,Wk,Wq,Wm]
    const unsigned short* Wb = Wp + ((size_t)wsel << 18);
    f32x4 acc[4][8] = {};
#pragma unroll 2
    for (int kb = 0; kb < 16; ++kb) {
        bf16x8 af[4], bf8[8];
#pragma unroll
        for (int j = 0; j < 8; ++j)   // issue all B loads first (latency pipelining)
            bf8[j] = *(const bf16x8*)(Wb + ((size_t)(((wv * 8 + j) * 16 + kb) * 64 + lane)) * 8);
#pragma unroll
        for (int i = 0; i < 4; ++i)
            af[i] = *(const bf16x8*)(&As[idxW(i * 16 + (lane & 15), kb * 4 + (lane >> 4))]);
#pragma unroll
        for (int j = 0; j < 8; ++j)
#pragma unroll
            for (int i = 0; i < 4; ++i)
                acc[i][j] = __builtin_amdgcn_mfma_f32_16x16x32_bf16(af[i], bf8[j], acc[i][j], 0, 0, 0);
    }

    if (srcSel < 2) {
        int panel = (srcSel == 0) ? pid : pid - 128;
        unsigned short* dst = (srcSel == 0) ? kh : vh;
        const float* bias = (srcSel == 0) ? bk : bv;
#pragma unroll
        for (int j = 0; j < 8; ++j) {
            int o = wv * 128 + j * 16 + (lane & 15);
            float bb = bias[o];
            int n = o >> 6, d = o & 63;
#pragma unroll
            for (int i = 0; i < 4; ++i)
#pragma unroll
                for (int reg = 0; reg < 4; ++reg) {
                    int r = panel * 64 + i * 16 + ((lane >> 4) << 2) + reg;
                    dst[(((size_t)((r >> 10) * 8 + n)) * 1024 + (r & 1023)) * 64 + d] =
                        f2bf(acc[i][j][reg] + bb);
                }
        }
    } else {
        int qi = pid - 256, b = qi >> 4, pp = qi & 15;
#pragma unroll
        for (int j = 0; j < 8; ++j) {
            int o = wv * 128 + j * 16 + (lane & 15);
            float bb = bq[o];
            int n = o >> 6, d = o & 63;
#pragma unroll
            for (int i = 0; i < 4; ++i)
#pragma unroll
                for (int reg = 0; reg < 4; ++reg) {
                    int p = pp * 64 + i * 16 + ((lane >> 4) << 2) + reg;
                    qh[(((size_t)(b * 8 + n)) * 1024 + p) * 64 + d] =
                        f2bf((acc[i][j][reg] + bb) * SCALE_Q);   // fold 1/8 * log2e
                }
        }
    }
}

// ---------- flash attention v2: T14 split staging, single softmax path ----------
// LDS 24KB: Qs (8KB, becomes per-wave P buffer after prologue) + Ks + Vs.
__global__ __launch_bounds__(256) void k_attn(unsigned short* qa,   // qh in, attnP out (alias)
                                              const unsigned short* __restrict__ kh,
                                              const unsigned short* __restrict__ vh,
                                              const int* __restrict__ mask) {
    __shared__ alignas(16) unsigned short Qs[64 * 64];   // Q staging, then P per wave
    __shared__ alignas(16) unsigned short Ks[64 * 64];
    __shared__ alignas(16) unsigned short Vs[64 * 64];   // transposed: [d][l]
    int tid = threadIdx.x, lane = tid & 63, wv = tid >> 6;
    int bn = blockIdx.x;
    int b = bn >> 3;
    int p0 = blockIdx.y * 64;
    const unsigned short* kbase = kh + ((size_t)bn) * 1024 * 64;
    const unsigned short* vbase = vh + ((size_t)bn) * 1024 * 64;
    const int* mbase = mask + (size_t)b * 1024;

    // ---- prologue: stage Q, grab frags ----
    {
        const unsigned short* g = qa + (((size_t)bn) * 1024 + p0) * 64;
#pragma unroll
        for (int s = 0; s < 2; ++s) {
            int idx = tid + s * 256, row = idx >> 3, c = idx & 7;
            *(uint4*)(&Qs[swz8(row, c)]) = *(const uint4*)(g + (size_t)row * 64 + c * 8);
        }
    }
    __syncthreads();
    bf16x8 aq0 = fragld(Qs, wv * 16 + (lane & 15), 0, lane);
    bf16x8 aq1 = fragld(Qs, wv * 16 + (lane & 15), 1, lane);
    unsigned short* Pw = &Qs[wv * 16 * 64];   // this wave's 16 Q-rows, now dead

    // ---- T14 staging registers: tile t in regs while tile t-1 computes ----
    int krow = tid >> 3, kch = tid & 7;                 // K: 2 x 16B per thread
    int vtk = (tid >> 4) * 4, vtn = (tid & 15) * 4;     // V: 4 x 8B per thread (transpose)
    uint4 kreg[2];
    ushort4 vreg[4];
    int mcur[4];
#pragma unroll
    for (int s = 0; s < 2; ++s)
        kreg[s] = *(const uint4*)(kbase + (size_t)(krow + s * 32) * 64 + kch * 8);
#pragma unroll
    for (int i = 0; i < 4; ++i)
        vreg[i] = *(const ushort4*)(vbase + (size_t)(vtk + i) * 64 + vtn);
#pragma unroll
    for (int j = 0; j < 4; ++j) mcur[j] = mbase[j * 16 + (lane & 15)];

    float mrow[4], lrow[4];
    f32x4 o4[4] = {};
#pragma unroll
    for (int r = 0; r < 4; ++r) { mrow[r] = -3e38f; lrow[r] = 0.f; }

    for (int t = 0; t < 16; ++t) {
        __syncthreads();   // previous tile's LDS reads done (t=0: Q frag reads done)
        // write staged regs -> LDS (compiler inserts vmcnt waits)
#pragma unroll
        for (int s = 0; s < 2; ++s)
            *(uint4*)(&Ks[swz8(krow + s * 32, kch)]) = kreg[s];
#pragma unroll
        for (int j = 0; j < 4; ++j) {
            int row = vtn + j;
            ushort4 w4;
            w4.x = vreg[0][j]; w4.y = vreg[1][j]; w4.z = vreg[2][j]; w4.w = vreg[3][j];
            *(ushort4*)(&Vs[row * 64 + (((vtk >> 3) ^ (row & 7)) << 3) + (vtk & 7)]) = w4;
        }
        __syncthreads();   // tile ready
        // issue next tile's global loads now; they complete under the compute below
        if (t < 15) {
            int l1 = (t + 1) * 64;
#pragma unroll
            for (int s = 0; s < 2; ++s)
                kreg[s] = *(const uint4*)(kbase + (size_t)(l1 + krow + s * 32) * 64 + kch * 8);
#pragma unroll
            for (int i = 0; i < 4; ++i)
                vreg[i] = *(const ushort4*)(vbase + (size_t)(l1 + vtk + i) * 64 + vtn);
        }

        // S = Q·K^T (log2 units)
        f32x4 s[4] = {};
#pragma unroll
        for (int j = 0; j < 4; ++j) {
            bf16x8 bk0 = fragld(Ks, j * 16 + (lane & 15), 0, lane);
            bf16x8 bk1 = fragld(Ks, j * 16 + (lane & 15), 1, lane);
            s[j] = __builtin_amdgcn_mfma_f32_16x16x32_bf16(aq0, bk0, s[j], 0, 0, 0);
            s[j] = __builtin_amdgcn_mfma_f32_16x16x32_bf16(aq1, bk1, s[j], 0, 0, 0);
        }
#pragma unroll
        for (int j = 0; j < 4; ++j) {
            if (mcur[j] != 0) {
#pragma unroll
                for (int reg = 0; reg < 4; ++reg) s[j][reg] = -1e9f;
            }
        }
        if (t < 15) {   // next tile's mask (after mcur consumed)
            int l1 = (t + 1) * 64;
#pragma unroll
            for (int j = 0; j < 4; ++j) mcur[j] = mbase[l1 + j * 16 + (lane & 15)];
        }

        // online softmax (single path, exp2 domain)
        float pvv[4][4], corr[4];
#pragma unroll
        for (int reg = 0; reg < 4; ++reg) {
            float mx = fmaxf(fmaxf(s[0][reg], s[1][reg]), fmaxf(s[2][reg], s[3][reg]));
#pragma unroll
            for (int off = 1; off < 16; off <<= 1) mx = fmaxf(mx, __shfl_xor(mx, off, 64));
            float mnew = fmaxf(mrow[reg], mx);
            corr[reg] = exp2f(mrow[reg] - mnew);
            mrow[reg] = mnew;
            float sum = 0.f;
#pragma unroll
            for (int j = 0; j < 4; ++j) {
                float p = exp2f(s[j][reg] - mnew);
                pvv[j][reg] = p; sum += p;
            }
#pragma unroll
            for (int off = 1; off < 16; off <<= 1) sum += __shfl_xor(sum, off, 64);
            lrow[reg] = lrow[reg] * corr[reg] + sum;
        }
        // P -> per-wave LDS slice (swizzled); rescale O; O += P·V
#pragma unroll
        for (int j = 0; j < 4; ++j) {
            int c = j * 16 + (lane & 15);
#pragma unroll
            for (int reg = 0; reg < 4; ++reg) {
                int pr = ((lane >> 4) << 2) + reg;
                Pw[pr * 64 + (((c >> 3) ^ (pr & 7)) << 3) + (c & 7)] = f2bf(pvv[j][reg]);
            }
        }
#pragma unroll
        for (int jd = 0; jd < 4; ++jd)
#pragma unroll
            for (int reg = 0; reg < 4; ++reg) o4[jd][reg] *= corr[reg];
#pragma unroll
        for (int kk = 0; kk < 2; ++kk) {
            bf16x8 ap = fragld(Pw, (lane & 15), kk, lane);
#pragma unroll
            for (int jd = 0; jd < 4; ++jd) {
                bf16x8 bvf = fragld(Vs, jd * 16 + (lane & 15), kk, lane);
                o4[jd] = __builtin_amdgcn_mfma_f32_16x16x32_bf16(ap, bvf, o4[jd], 0, 0, 0);
            }
        }
    }
    // epilogue: normalize; per-wave transpose to [p][d]; store frag-native over qh region.
    float inv[4];
#pragma unroll
    for (int reg = 0; reg < 4; ++reg) inv[reg] = 1.f / lrow[reg];
    unsigned short* Ow = Pw;  // [16 p][64 d], chunk-swizzled by p&7
#pragma unroll
    for (int jd = 0; jd < 4; ++jd) {
        int d = jd * 16 + (lane & 15);
        int ch = d >> 3, doff = d & 7;
#pragma unroll
        for (int reg = 0; reg < 4; ++reg) {
            int pr = ((lane >> 4) << 2) + reg;
            Ow[pr * 64 + ((ch ^ (pr & 7)) << 3) + doff] = f2bf(o4[jd][reg] * inv[reg]);
        }
    }
    size_t base = ((size_t)bn * 16 + blockIdx.y) * 4096;
#pragma unroll
    for (int h = 0; h < 2; ++h) {
        int p = lane & 15;
        int ch = h * 4 + (lane >> 4);
        uint4 w = *(const uint4*)(&Ow[p * 64 + ((ch ^ (p & 7)) << 3)]);
        *(uint4*)(qa + base + (size_t)(wv * 2 + h) * 512 + (size_t)lane * 8) = w;
    }
}

// ---------- final 1x1 conv: zero-LDS, zero-barrier GEMM + bias + relu ----------
__global__ __launch_bounds__(256, 2) void g_final(const unsigned short* __restrict__ aP,
                                                  const unsigned short* __restrict__ Wm8,
                                                  const float* __restrict__ bm,
                                                  float* __restrict__ out) {
    int tid = threadIdx.x, lane = tid & 63, wv = tid >> 6;
    int wr = wv >> 1, wc = wv & 1;
    int b = blockIdx.z, m0 = blockIdx.x * 128, n0 = blockIdx.y * 128;
    int onb = m0 / 16 + wr * 4;     // A 16-row block base (o)
    int pnb = n0 / 16 + wc * 4;     // B 16-row block base (p)
    f32x4 acc[4][4] = {};
#pragma unroll 2
    for (int kb = 0; kb < 16; ++kb) {
        int nh = kb >> 1, h = kb & 1, bn = b * 8 + nh;
        bf16x8 af[4], bf8[4];
#pragma unroll
        for (int i = 0; i < 4; ++i)
            af[i] = *(const bf16x8*)(Wm8 + ((size_t)(((onb + i) * 16 + kb) * 64 + lane)) * 8);
#pragma unroll
        for (int j = 0; j < 4; ++j) {
            int pb = pnb + j;
            bf8[j] = *(const bf16x8*)(aP + ((size_t)bn * 16 + (pb >> 2)) * 4096 +
                                      (size_t)((pb & 3) * 2 + h) * 512 + (size_t)lane * 8);
        }
#pragma unroll
        for (int i = 0; i < 4; ++i)
#pragma unroll
            for (int j = 0; j < 4; ++j)
                acc[i][j] = __builtin_amdgcn_mfma_f32_16x16x32_bf16(af[i], bf8[j], acc[i][j], 0, 0, 0);
    }
#pragma unroll
    for (int i = 0; i < 4; ++i)
#pragma unroll
        for (int reg = 0; reg < 4; ++reg) {
            int o = m0 + wr * 64 + i * 16 + ((lane >> 4) << 2) + reg;
            float bb = bm[o];
#pragma unroll
            for (int j = 0; j < 4; ++j) {
                int p = n0 + wc * 64 + j * 16 + (lane & 15);
                out[((size_t)(b * 512 + o)) * 1024 + p] = fmaxf(acc[i][j][reg] + bb, 0.f);
            }
        }
}

extern "C" void kernel_launch(void* const* d_in, const int* in_sizes, int n_in,
                              void* d_out, int out_size, void* d_ws, size_t ws_size,
                              hipStream_t stream) {
    const float* v  = (const float*)d_in[0];
    const float* k  = (const float*)d_in[1];
    const float* q  = (const float*)d_in[2];
    const int*   mask = (const int*)d_in[3];   // JAX bool -> int32
    const float* Wv = (const float*)d_in[4];
    const float* bv = (const float*)d_in[5];
    const float* Wk = (const float*)d_in[6];
    const float* bk = (const float*)d_in[7];
    const float* Wq = (const float*)d_in[8];
    const float* bq = (const float*)d_in[9];
    const float* Wm = (const float*)d_in[10];
    const float* bm = (const float*)d_in[11];
    float* out = (float*)d_out;

    const size_t E = (size_t)8 * 8 * 1024 * 64;   // 4,194,304 shorts = 8 MB per region
    unsigned short* kh = (unsigned short*)d_ws;
    unsigned short* vh = kh + E;
    unsigned short* qh = vh + E;                  // attnP aliases qh after k_attn
    unsigned short* Wp = qh + E;                  // 4 x 512KB frag-packed weights
    // total: 26 MB

    dim3 blk(256);
    ck_w  <<<512, blk, 0, stream>>>(Wv, Wk, Wq, Wm, Wp);
    g_proj<<<384, blk, 0, stream>>>(k, v, q, Wp, bk, bv, bq, kh, vh, qh);
    k_attn<<<dim3(64, 16), blk, 0, stream>>>(qh, kh, vh, mask);
    g_final<<<dim3(4, 8, 8), blk, 0, stream>>>(qh, Wp + 3 * 262144, bm, out);
}

// Round 6
// 214.979 us; speedup vs baseline: 1.1183x; 1.0438x over previous
//
#include <hip/hip_runtime.h>

// ---------- types ----------
typedef __attribute__((ext_vector_type(8))) __bf16 bf16x8;
typedef __attribute__((ext_vector_type(4))) float  f32x4;

#define SCALE_Q 0.1803368801111204f   // 0.125 * log2(e): QK^T in log2 units

__device__ __forceinline__ unsigned short f2bf(float f) {
    unsigned int u = __builtin_bit_cast(unsigned int, f);
    u += 0x7fffu + ((u >> 16) & 1u);          // RNE
    return (unsigned short)(u >> 16);
}
__device__ __forceinline__ unsigned int pack2(float a, float b) {
    return (unsigned int)f2bf(a) | ((unsigned int)f2bf(b) << 16);
}

// [rows][512 bf16] LDS tile, 8-elem-chunk XOR-swizzled (low 3 chunk bits ^ row&7)
__device__ __forceinline__ int idxW(int row, int ch) {
    return row * 512 + (((ch & ~7) | ((ch ^ row) & 7)) << 3);
}
// [rows][64 bf16] LDS tile, chunk-swizzled: location x holds data chunk x^(row&7)
__device__ __forceinline__ int swz8(int row, int chunk) {
    return row * 64 + ((chunk ^ (row & 7)) << 3);
}
__device__ __forceinline__ bf16x8 fragld(const unsigned short* lds, int row, int kk, int lane) {
    return *(const bf16x8*)(lds + swz8(row, kk * 4 + (lane >> 4)));
}

// async 16B/lane global->LDS; dest = wave-uniform base + lane*16
__device__ __forceinline__ void gload16(const unsigned short* g, unsigned short* l) {
    __builtin_amdgcn_global_load_lds((const __attribute__((address_space(1))) void*)g,
                                     (__attribute__((address_space(3))) void*)l, 16, 0, 0);
}
// stage a 64-row x 64-short tile, 4 waves x 16 rows each; row stride ldg shorts
__device__ __forceinline__ void stage16(const unsigned short* g, int ldg,
                                        unsigned short* lds, int lane, int wv) {
    const unsigned short* gp = g + (size_t)(wv * 16 + (lane >> 3)) * ldg + (lane & 7) * 8;
#pragma unroll
    for (int i = 0; i < 2; ++i)
        gload16(gp + (size_t)(i * 8) * ldg, lds + (wv * 16 + i * 8) * 64);
}

// ---------- weight pre-pack: f32 -> bf16 fragment-native ----------
__global__ __launch_bounds__(256) void ck_w(const float* __restrict__ Wv, const float* __restrict__ Wk,
                                            const float* __restrict__ Wq, const float* __restrict__ Wm,
                                            unsigned short* __restrict__ Wp) {
    int tid = threadIdx.x, lane = tid & 63;
    int gw = blockIdx.x * 4 + (tid >> 6);       // 2048 wave-tasks
    int w = gw >> 9, rem = gw & 511;
    int nb = rem >> 4, kb = rem & 15;
    const float* src = (w == 0) ? Wv : (w == 1) ? Wk : (w == 2) ? Wq : Wm;
    const float* gp = src + (size_t)(nb * 16 + (lane & 15)) * 512 + kb * 32 + (lane >> 4) * 8;
    float4 v0 = *(const float4*)gp, v1 = *(const float4*)(gp + 4);
    uint4 o;
    o.x = pack2(v0.x, v0.y); o.y = pack2(v0.z, v0.w);
    o.z = pack2(v1.x, v1.y); o.w = pack2(v1.z, v1.w);
    *(uint4*)(Wp + ((size_t)w << 18) + ((size_t)((nb * 16 + kb) * 64 + lane)) * 8) = o;
}

// ---------- fused projection GEMM ----------
// pid<128: kh from k (pre-swizzled [bn][l][dsw]); <256: vhT from v ([bn][d][lsw]);
// else qh from q (pre-swizzled [bn][p][dsw], x SCALE_Q).
__global__ __launch_bounds__(256, 2) void g_proj(const float* __restrict__ kin,
                                                 const float* __restrict__ vin,
                                                 const float* __restrict__ qin,
                                                 const unsigned short* __restrict__ Wp,
                                                 const float* __restrict__ bk,
                                                 const float* __restrict__ bv,
                                                 const float* __restrict__ bq,
                                                 unsigned short* __restrict__ kh,
                                                 unsigned short* __restrict__ vhT,
                                                 unsigned short* __restrict__ qh) {
    __shared__ alignas(16) unsigned short As[64 * 512];   // 64 KB (A-stage, then C-transpose)
    int tid = threadIdx.x, lane = tid & 63, wv = tid >> 6;
    int pid = blockIdx.x;
    int srcSel = (pid < 128) ? 0 : (pid < 256) ? 1 : 2;

    // ---- A stage ----
    if (srcSel < 2) {
        int panel = (srcSel == 0) ? pid : pid - 128;
        const float* src = ((srcSel == 0) ? kin : vin) + (size_t)panel * 64 * 512;
#pragma unroll
        for (int it = 0; it < 16; ++it) {
            int id = it * 256 + tid, row = id >> 6, ch = id & 63;
            const float* gp = src + (size_t)row * 512 + ch * 8;
            float4 a0 = *(const float4*)gp, a1 = *(const float4*)(gp + 4);
            uint4 w;
            w.x = pack2(a0.x, a0.y); w.y = pack2(a0.z, a0.w);
            w.z = pack2(a1.x, a1.y); w.w = pack2(a1.z, a1.w);
            *(uint4*)(&As[idxW(row, ch)]) = w;
        }
    } else {
        int qi = pid - 256, b = qi >> 4, pp = qi & 15;
        const float* src = qin + (size_t)b * 512 * 1024 + pp * 64;
#pragma unroll
        for (int cc = 0; cc < 8; ++cc) {
            int c0 = cc * 64 + (tid >> 4) * 4;
            int pl = (tid & 15) * 4;
            float rr[4][4];
#pragma unroll
            for (int i = 0; i < 4; ++i) {
                float4 t4 = *(const float4*)(src + (size_t)(c0 + i) * 1024 + pl);
                rr[i][0] = t4.x; rr[i][1] = t4.y; rr[i][2] = t4.z; rr[i][3] = t4.w;
            }
#pragma unroll
            for (int j = 0; j < 4; ++j) {
                int row = pl + j, chunk = c0 >> 3, off = c0 & 7;
                uint2 w2;
                w2.x = pack2(rr[0][j], rr[1][j]);
                w2.y = pack2(rr[2][j], rr[3][j]);
                *(uint2*)(&As[row * 512 + (((chunk & ~7) | ((chunk ^ row) & 7)) << 3) + off]) = w2;
            }
        }
    }
    __syncthreads();

    int wsel = (srcSel == 0) ? 1 : (srcSel == 1) ? 0 : 2;   // pack order [Wv,Wk,Wq,Wm]
    const unsigned short* Wb = Wp + ((size_t)wsel << 18);
    f32x4 acc[4][8] = {};
#pragma unroll 2
    for (int kb = 0; kb < 16; ++kb) {
        bf16x8 af[4], bf8[8];
#pragma unroll
        for (int j = 0; j < 8; ++j)
            bf8[j] = *(const bf16x8*)(Wb + ((size_t)(((wv * 8 + j) * 16 + kb) * 64 + lane)) * 8);
#pragma unroll
        for (int i = 0; i < 4; ++i)
            af[i] = *(const bf16x8*)(&As[idxW(i * 16 + (lane & 15), kb * 4 + (lane >> 4))]);
#pragma unroll
        for (int j = 0; j < 8; ++j)
#pragma unroll
            for (int i = 0; i < 4; ++i)
                acc[i][j] = __builtin_amdgcn_mfma_f32_16x16x32_bf16(af[i], bf8[j], acc[i][j], 0, 0, 0);
    }

    // ---- epilogues ----
    if (srcSel == 1) {
        // V: direct reg->global, transposed + pre-swizzled: vhT[bn][d][win + ((lc^ (d&7))<<3)+l&7]
        int panel = pid - 128, b = panel >> 4;
        int win = (panel & 15) * 64;
#pragma unroll
        for (int j = 0; j < 8; ++j) {
            int o = wv * 128 + j * 16 + (lane & 15);
            float bb = bv[o];
            int n = o >> 6, d = o & 63;
            size_t bnbase = ((size_t)(b * 8 + n)) * 65536 + (size_t)d * 1024 + win;
#pragma unroll
            for (int i = 0; i < 4; ++i) {
                int l0 = i * 16 + ((lane >> 4) << 2);
                uint2 w2;
                w2.x = pack2(acc[i][j][0] + bb, acc[i][j][1] + bb);
                w2.y = pack2(acc[i][j][2] + bb, acc[i][j][3] + bb);
                int off = (((l0 >> 3) ^ (d & 7)) << 3) + (l0 & 7);
                *(uint2*)(&vhT[bnbase + off]) = w2;
            }
        }
    } else {
        // K / Q: transpose via As (chunk-swizzled), then linear 16B copies out.
        const float* bias = (srcSel == 0) ? bk : bq;
        float scl = (srcSel == 0) ? 1.f : SCALE_Q;
        __syncthreads();   // A-tile reads done; reuse As
#pragma unroll
        for (int j = 0; j < 8; ++j) {
            int o = wv * 128 + j * 16 + (lane & 15);
            float bb = bias[o];
            int Cd = o >> 3, ob = o & 7;
#pragma unroll
            for (int i = 0; i < 4; ++i)
#pragma unroll
                for (int reg = 0; reg < 4; ++reg) {
                    int l = i * 16 + ((lane >> 4) << 2) + reg;
                    int Cs = (Cd & ~7) | ((Cd ^ l) & 7);
                    As[l * 512 + Cs * 8 + ob] = f2bf((acc[i][j][reg] + bb) * scl);
                }
        }
        __syncthreads();
        unsigned short* dst;
        int b, rbase;
        if (srcSel == 0) { b = pid >> 4; rbase = (pid & 15) * 64; dst = kh; }
        else { int qi = pid - 256; b = qi >> 4; rbase = (qi & 15) * 64; dst = qh; }
#pragma unroll
        for (int e = 0; e < 16; ++e) {
            int n = e >> 1, l = (e & 1) * 32 + (tid >> 3), ch = tid & 7;
            uint4 w = *(const uint4*)(&As[l * 512 + (n * 8 + ch) * 8]);
            *(uint4*)(&dst[(((size_t)(b * 8 + n)) * 1024 + rbase + l) * 64 + ch * 8]) = w;
        }
    }
}

// ---------- flash attention v3: all operands global_load_lds-direct, dbuf K/V ----------
__global__ __launch_bounds__(256) void k_attn(unsigned short* qa,   // qh in, attnP out (alias)
                                              const unsigned short* __restrict__ kh,
                                              const unsigned short* __restrict__ vhT,
                                              const int* __restrict__ mask) {
    __shared__ alignas(16) unsigned short Qs[64 * 64];      // Q, then per-wave P
    __shared__ alignas(16) unsigned short Ks[2][64 * 64];
    __shared__ alignas(16) unsigned short Vs[2][64 * 64];   // [d][l] (pre-transposed global)
    int tid = threadIdx.x, lane = tid & 63, wv = tid >> 6;
    int bn = blockIdx.x;
    int b = bn >> 3;
    int p0 = blockIdx.y * 64;
    const unsigned short* kbase = kh + ((size_t)bn) * 65536;
    const unsigned short* vbase = vhT + ((size_t)bn) * 65536;
    const int* mbase = mask + (size_t)b * 1024;

    // prologue: DMA Q + tile0 K/V
    stage16(qa + (((size_t)bn) * 1024 + p0) * 64, 64, Qs, lane, wv);
    stage16(kbase, 64, Ks[0], lane, wv);
    stage16(vbase, 1024, Vs[0], lane, wv);
    __syncthreads();
    bf16x8 aq0 = fragld(Qs, wv * 16 + (lane & 15), 0, lane);
    bf16x8 aq1 = fragld(Qs, wv * 16 + (lane & 15), 1, lane);
    unsigned short* Pw = &Qs[wv * 16 * 64];   // wave-local; Qs dead after frag reads

    float mrow[4], lrow[4];
    f32x4 o4[4] = {};
#pragma unroll
    for (int r = 0; r < 4; ++r) { mrow[r] = -3e38f; lrow[r] = 0.f; }

#pragma unroll 2
    for (int t = 0; t < 16; ++t) {
        int cur = t & 1;
        if (t < 15) {   // prefetch next tile; lands before end-of-iter barrier drain
            int l1 = (t + 1) * 64;
            stage16(kbase + (size_t)l1 * 64, 64, Ks[cur ^ 1], lane, wv);
            stage16(vbase + l1, 1024, Vs[cur ^ 1], lane, wv);
        }
        int l0 = t * 64;
        int mc[4];
#pragma unroll
        for (int j = 0; j < 4; ++j) mc[j] = mbase[l0 + j * 16 + (lane & 15)];

        f32x4 s[4] = {};
#pragma unroll
        for (int j = 0; j < 4; ++j) {
            bf16x8 bk0 = fragld(Ks[cur], j * 16 + (lane & 15), 0, lane);
            bf16x8 bk1 = fragld(Ks[cur], j * 16 + (lane & 15), 1, lane);
            s[j] = __builtin_amdgcn_mfma_f32_16x16x32_bf16(aq0, bk0, s[j], 0, 0, 0);
            s[j] = __builtin_amdgcn_mfma_f32_16x16x32_bf16(aq1, bk1, s[j], 0, 0, 0);
        }
#pragma unroll
        for (int j = 0; j < 4; ++j) {
            if (mc[j] != 0) {
#pragma unroll
                for (int reg = 0; reg < 4; ++reg) s[j][reg] = -1e9f;
            }
        }
        // online softmax (exp2 domain)
        float pvv[4][4], corr[4];
#pragma unroll
        for (int reg = 0; reg < 4; ++reg) {
            float mx = fmaxf(fmaxf(s[0][reg], s[1][reg]), fmaxf(s[2][reg], s[3][reg]));
#pragma unroll
            for (int off = 1; off < 16; off <<= 1) mx = fmaxf(mx, __shfl_xor(mx, off, 64));
            float mnew = fmaxf(mrow[reg], mx);
            corr[reg] = exp2f(mrow[reg] - mnew);
            mrow[reg] = mnew;
            float sum = 0.f;
#pragma unroll
            for (int j = 0; j < 4; ++j) {
                float p = exp2f(s[j][reg] - mnew);
                pvv[j][reg] = p; sum += p;
            }
#pragma unroll
            for (int off = 1; off < 16; off <<= 1) sum += __shfl_xor(sum, off, 64);
            lrow[reg] = lrow[reg] * corr[reg] + sum;
        }
        // P -> wave-local LDS (swizzled); rescale O; O += P·V
#pragma unroll
        for (int j = 0; j < 4; ++j) {
            int c = j * 16 + (lane & 15);
#pragma unroll
            for (int reg = 0; reg < 4; ++reg) {
                int pr = ((lane >> 4) << 2) + reg;
                Pw[pr * 64 + (((c >> 3) ^ (pr & 7)) << 3) + (c & 7)] = f2bf(pvv[j][reg]);
            }
        }
#pragma unroll
        for (int jd = 0; jd < 4; ++jd)
#pragma unroll
            for (int reg = 0; reg < 4; ++reg) o4[jd][reg] *= corr[reg];
#pragma unroll
        for (int kk = 0; kk < 2; ++kk) {
            bf16x8 ap = fragld(Pw, (lane & 15), kk, lane);
#pragma unroll
            for (int jd = 0; jd < 4; ++jd) {
                bf16x8 bvf = fragld(Vs[cur], jd * 16 + (lane & 15), kk, lane);
                o4[jd] = __builtin_amdgcn_mfma_f32_16x16x32_bf16(ap, bvf, o4[jd], 0, 0, 0);
            }
        }
        __syncthreads();   // drains prefetch vmcnt + all waves done with cur buffers
    }
    // epilogue: normalize; transpose to [p][d]; frag-native store over qh region
    float inv[4];
#pragma unroll
    for (int reg = 0; reg < 4; ++reg) inv[reg] = 1.f / lrow[reg];
    unsigned short* Ow = Pw;  // [16 p][64 d], chunk-swizzled by p&7
#pragma unroll
    for (int jd = 0; jd < 4; ++jd) {
        int d = jd * 16 + (lane & 15);
        int ch = d >> 3, doff = d & 7;
#pragma unroll
        for (int reg = 0; reg < 4; ++reg) {
            int pr = ((lane >> 4) << 2) + reg;
            Ow[pr * 64 + ((ch ^ (pr & 7)) << 3) + doff] = f2bf(o4[jd][reg] * inv[reg]);
        }
    }
    size_t base = ((size_t)bn * 16 + blockIdx.y) * 4096;
#pragma unroll
    for (int h = 0; h < 2; ++h) {
        int p = lane & 15;
        int ch = h * 4 + (lane >> 4);
        uint4 w = *(const uint4*)(&Ow[p * 64 + ((ch ^ (p & 7)) << 3)]);
        *(uint4*)(qa + base + (size_t)(wv * 2 + h) * 512 + (size_t)lane * 8) = w;
    }
}

// ---------- final 1x1 conv: zero-LDS, zero-barrier GEMM + bias + relu ----------
__global__ __launch_bounds__(256, 2) void g_final(const unsigned short* __restrict__ aP,
                                                  const unsigned short* __restrict__ Wm8,
                                                  const float* __restrict__ bm,
                                                  float* __restrict__ out) {
    int tid = threadIdx.x, lane = tid & 63, wv = tid >> 6;
    int wr = wv >> 1, wc = wv & 1;
    int b = blockIdx.z, m0 = blockIdx.x * 128, n0 = blockIdx.y * 128;
    int onb = m0 / 16 + wr * 4;
    int pnb = n0 / 16 + wc * 4;
    f32x4 acc[4][4] = {};
#pragma unroll 2
    for (int kb = 0; kb < 16; ++kb) {
        int nh = kb >> 1, h = kb & 1, bn = b * 8 + nh;
        bf16x8 af[4], bf8[4];
#pragma unroll
        for (int i = 0; i < 4; ++i)
            af[i] = *(const bf16x8*)(Wm8 + ((size_t)(((onb + i) * 16 + kb) * 64 + lane)) * 8);
#pragma unroll
        for (int j = 0; j < 4; ++j) {
            int pb = pnb + j;
            bf8[j] = *(const bf16x8*)(aP + ((size_t)bn * 16 + (pb >> 2)) * 4096 +
                                      (size_t)((pb & 3) * 2 + h) * 512 + (size_t)lane * 8);
        }
#pragma unroll
        for (int i = 0; i < 4; ++i)
#pragma unroll
            for (int j = 0; j < 4; ++j)
                acc[i][j] = __builtin_amdgcn_mfma_f32_16x16x32_bf16(af[i], bf8[j], acc[i][j], 0, 0, 0);
    }
#pragma unroll
    for (int i = 0; i < 4; ++i)
#pragma unroll
        for (int reg = 0; reg < 4; ++reg) {
            int o = m0 + wr * 64 + i * 16 + ((lane >> 4) << 2) + reg;
            float bb = bm[o];
#pragma unroll
            for (int j = 0; j < 4; ++j) {
                int p = n0 + wc * 64 + j * 16 + (lane & 15);
                out[((size_t)(b * 512 + o)) * 1024 + p] = fmaxf(acc[i][j][reg] + bb, 0.f);
            }
        }
}

extern "C" void kernel_launch(void* const* d_in, const int* in_sizes, int n_in,
                              void* d_out, int out_size, void* d_ws, size_t ws_size,
                              hipStream_t stream) {
    const float* v  = (const float*)d_in[0];
    const float* k  = (const float*)d_in[1];
    const float* q  = (const float*)d_in[2];
    const int*   mask = (const int*)d_in[3];   // JAX bool -> int32
    const float* Wv = (const float*)d_in[4];
    const float* bv = (const float*)d_in[5];
    const float* Wk = (const float*)d_in[6];
    const float* bk = (const float*)d_in[7];
    const float* Wq = (const float*)d_in[8];
    const float* bq = (const float*)d_in[9];
    const float* Wm = (const float*)d_in[10];
    const float* bm = (const float*)d_in[11];
    float* out = (float*)d_out;

    const size_t E = (size_t)8 * 8 * 1024 * 64;   // 4,194,304 shorts = 8 MB per region
    unsigned short* kh  = (unsigned short*)d_ws;  // pre-swizzled [bn][l][dsw]
    unsigned short* vhT = kh + E;                 // pre-swizzled [bn][d][lsw]
    unsigned short* qh  = vhT + E;                // pre-swizzled [bn][p][dsw]; attnP alias
    unsigned short* Wp  = qh + E;                 // 4 x 512KB frag-packed weights

    dim3 blk(256);
    ck_w  <<<512, blk, 0, stream>>>(Wv, Wk, Wq, Wm, Wp);
    g_proj<<<384, blk, 0, stream>>>(k, v, q, Wp, bk, bv, bq, kh, vhT, qh);
    k_attn<<<dim3(64, 16), blk, 0, stream>>>(qh, kh, vhT, mask);
    g_final<<<dim3(4, 8, 8), blk, 0, stream>>>(qh, Wp + 3 * 262144, bm, out);
}